// Round 6
// baseline (467.572 us; speedup 1.0000x reference)
//
#include <hip/hip_runtime.h>
#include <hip/hip_bf16.h>
#include <math.h>

typedef __attribute__((ext_vector_type(4))) float f32x4;
typedef __attribute__((ext_vector_type(8))) short bf16x8;

#define T_TOK 2048
#define H_DIM 1024
#define I_DIM 2048
#define E_NUM 8

// RNE float -> bf16
__device__ inline unsigned short f2bf(float f) {
  union { float f; unsigned int u; } v; v.f = f;
  unsigned int r = v.u + 0x7fffu + ((v.u >> 16) & 1u);
  return (unsigned short)(r >> 16);
}
__device__ inline unsigned int pack2(float a, float b) {
  return (unsigned int)f2bf(a) | ((unsigned int)f2bf(b) << 16);
}

// async global->LDS, 16 bytes per lane
__device__ inline void gld16(const void* g, void* l) {
  __builtin_amdgcn_global_load_lds((const __attribute__((address_space(1))) void*)g,
                                   (__attribute__((address_space(3))) void*)l, 16, 0, 0);
}

// ---------------- pipelined 4x(paired 64x64) fp32 [R][C] -> bf16 [C][R] transpose ----------
// One block handles rows [rpg*512, rpg*512+512) x cols [ct*64, ct*64+64), as 4 sequential
// 128x64 tile-pairs. Tile t+1's 8 float4 loads are issued while tile t is in its LDS/store
// phase, so HBM latency hides under the store phase instead of serializing per tile.
__device__ inline void transpose_quad(const float* __restrict__ ip, unsigned short* __restrict__ op,
                                      int R, int C, int rpg, int ct, char* smem)
{
  unsigned short (*tl)[66] = (unsigned short (*)[66])smem;   // [2*64 cols][64 rows + pad2]
  int c0 = ct * 64;
  int tid = threadIdx.x;
  int rq = (tid >> 4) * 4;        // 4 consecutive rows within 64-row tile
  int c4 = (tid & 15) * 4;        // 4 consecutive cols
  int cs = tid >> 3, r8 = (tid & 7) * 8;   // store-phase indices

  float4 v[8];
  {
    int r0 = rpg * 512;
    const float* b0 = ip + (size_t)(r0 + rq) * C + c0 + c4;
    const float* b1 = b0 + (size_t)64 * C;
#pragma unroll
    for (int q = 0; q < 4; ++q) { v[q] = *(const float4*)(b0 + q * C); v[4 + q] = *(const float4*)(b1 + q * C); }
  }
#pragma unroll
  for (int t = 0; t < 4; ++t) {
    const float* f = (const float*)v;
#pragma unroll
    for (int j = 0; j < 4; ++j) {
      *(unsigned int*)&tl[c4 + j][rq]          = pack2(f[0 * 4 + j], f[1 * 4 + j]);
      *(unsigned int*)&tl[c4 + j][rq + 2]      = pack2(f[2 * 4 + j], f[3 * 4 + j]);
      *(unsigned int*)&tl[64 + c4 + j][rq]     = pack2(f[4 * 4 + j], f[5 * 4 + j]);
      *(unsigned int*)&tl[64 + c4 + j][rq + 2] = pack2(f[6 * 4 + j], f[7 * 4 + j]);
    }
    if (t < 3) {                 // issue next tile's loads; in flight across both barriers
      int rn = rpg * 512 + (t + 1) * 128;
      const float* n0 = ip + (size_t)(rn + rq) * C + c0 + c4;
      const float* n1 = n0 + (size_t)64 * C;
#pragma unroll
      for (int q = 0; q < 4; ++q) { v[q] = *(const float4*)(n0 + q * C); v[4 + q] = *(const float4*)(n1 + q * C); }
    }
    __syncthreads();
    int r0t = rpg * 512 + t * 128;
#pragma unroll
    for (int it = 0; it < 2; ++it) {
      int cc = cs + it * 32;
#pragma unroll
      for (int p = 0; p < 2; ++p) {
        uint4 o;
        o.x = *(const unsigned int*)&tl[p * 64 + cc][r8];
        o.y = *(const unsigned int*)&tl[p * 64 + cc][r8 + 2];
        o.z = *(const unsigned int*)&tl[p * 64 + cc][r8 + 4];
        o.w = *(const unsigned int*)&tl[p * 64 + cc][r8 + 6];
        *(uint4*)(op + (size_t)(c0 + cc) * R + r0t + p * 64 + r8) = o;
      }
    }
    __syncthreads();
  }
}

// ---------------- kernel 1: gate (+x cast) fused with transpose of w1,w3,w2 ----------------
// blocks [0,512): gate; [512,1536): w1/w3 quad-tiles; [1536,2048): w2 quad-tiles
__global__ __launch_bounds__(256) void gate_t13(
    const float* __restrict__ x, const float* __restrict__ gw, const float* __restrict__ gb,
    int* __restrict__ rec_e, float* __restrict__ rec_w, unsigned short* __restrict__ xb,
    const float* __restrict__ w1, const float* __restrict__ w3,
    unsigned short* __restrict__ w1t, unsigned short* __restrict__ w3t,
    const float* __restrict__ w2, unsigned short* __restrict__ w2t)
{
  __shared__ __align__(16) char smem[128 * 66 * 2];
  int bx = blockIdx.x;
  if (bx >= 1536) {
    int idx = bx - 1536;       // w2: [E][I][H] -> w2t [E][H][I]
    int e = idx >> 6;          // 0..7
    int sub = idx & 63;
    int rpg = sub & 3;         // R = I_DIM -> 4 quad-groups
    int ct = sub >> 2;         // C = H_DIM -> 16 col tiles
    const float* ip = w2 + (size_t)e * ((size_t)H_DIM * I_DIM);
    unsigned short* op = w2t + (size_t)e * ((size_t)H_DIM * I_DIM);
    transpose_quad(ip, op, I_DIM, H_DIM, rpg, ct, smem);
    return;
  }
  if (bx >= 512) {
    int idx = bx - 512;
    int m = idx >> 6;          // 0..15
    int sub = idx & 63;
    int rpg = sub & 1;         // R = H_DIM -> 2 quad-groups
    int ct = sub >> 1;         // C = I_DIM -> 32 col tiles
    const float* ip = (m < 8 ? w1 : w3) + (size_t)(m & 7) * ((size_t)H_DIM * I_DIM);
    unsigned short* op = (m < 8 ? w1t : w3t) + (size_t)(m & 7) * ((size_t)H_DIM * I_DIM);
    transpose_quad(ip, op, H_DIM, I_DIM, rpg, ct, smem);
    return;
  }
  int wv = threadIdx.x >> 6, lane = threadIdx.x & 63;
  int t = bx * 4 + wv;
  const float* xr = x + (size_t)t * H_DIM;
  unsigned short* xo = xb + (size_t)t * H_DIM;
  float acc[8];
#pragma unroll
  for (int e = 0; e < 8; ++e) acc[e] = 0.f;
  for (int i = 0; i < H_DIM / 64; ++i) {
    int h = i * 64 + lane;
    float xv = xr[h];
    xo[h] = f2bf(xv);
    const float4* g = (const float4*)(gw + (size_t)h * 8);
    float4 g0 = g[0], g1 = g[1];
    acc[0] += xv * g0.x; acc[1] += xv * g0.y; acc[2] += xv * g0.z; acc[3] += xv * g0.w;
    acc[4] += xv * g1.x; acc[5] += xv * g1.y; acc[6] += xv * g1.z; acc[7] += xv * g1.w;
  }
#pragma unroll
  for (int s = 1; s < 64; s <<= 1) {
#pragma unroll
    for (int e = 0; e < 8; ++e) acc[e] += __shfl_xor(acc[e], s);
  }
  if (lane == 0) {
    float l[8];
#pragma unroll
    for (int e = 0; e < 8; ++e) l[e] = acc[e] + gb[e];
    int e0 = 0;
    for (int e = 1; e < 8; ++e) if (l[e] > l[e0]) e0 = e;
    int e1 = (e0 == 0) ? 1 : 0;
    for (int e = 0; e < 8; ++e) if (e != e0 && l[e] > l[e1]) e1 = e;
    float w0 = 1.f / (1.f + expf(l[e1] - l[e0]));
    rec_e[t * 2]     = e0; rec_e[t * 2 + 1] = e1;
    rec_w[t * 2]     = w0; rec_w[t * 2 + 1] = 1.f - w0;
  }
}

// ---------------- routing: 8 blocks, one per expert ----------------
__global__ __launch_bounds__(256) void route8(
    const int* __restrict__ rec_e, const float* __restrict__ rec_w,
    int* __restrict__ counts_g, int* __restrict__ list_tok, float* __restrict__ list_w)
{
  __shared__ int cnt[8];
  __shared__ int fill;
  int e = blockIdx.x;
  int tid = threadIdx.x;
  if (tid < 8) cnt[tid] = 0;
  if (tid == 0) fill = 0;
  __syncthreads();
  int e_loc[16];
  int c_loc[8];
#pragma unroll
  for (int k = 0; k < 8; ++k) c_loc[k] = 0;
#pragma unroll
  for (int it = 0; it < 16; ++it) {
    e_loc[it] = rec_e[it * 256 + tid] & 7;
    c_loc[e_loc[it]]++;
  }
#pragma unroll
  for (int k = 0; k < 8; ++k) if (c_loc[k]) atomicAdd(&cnt[k], c_loc[k]);
  __syncthreads();
  if (e == 0 && tid < 8) counts_g[tid] = cnt[tid];
  int base = 0;
#pragma unroll
  for (int k = 0; k < 8; ++k) if (k < e) base += cnt[k];
#pragma unroll
  for (int it = 0; it < 16; ++it) {
    if (e_loc[it] == e) {
      int i = it * 256 + tid;
      int pos = atomicAdd(&fill, 1);
      list_tok[base + pos] = i;            // i = (t<<1)|k
      list_w[base + pos]   = rec_w[i];
    }
  }
}

// ---------------- gemm1: 128x128 dual (B1,B3), BK=32, 2-phase dbuf, swizzled LDS ----------------
__global__ __launch_bounds__(256, 3) void gemm1(
    const unsigned short* __restrict__ xb,
    const unsigned short* __restrict__ w1t,
    const unsigned short* __restrict__ w3t,
    const int* __restrict__ counts,
    const int* __restrict__ list_tok,
    unsigned short* __restrict__ hbuf)
{
  __shared__ __align__(16) char smem[49152];
  int bx = blockIdx.x;
  int e = bx >> 9;
  int y = (bx >> 4) & 31;
  int ix = bx & 15;
  int nbase = 0;
#pragma unroll
  for (int i = 0; i < 8; ++i) if (i < e) nbase += counts[i];
  int n_e = counts[e];
  int t0 = y * 128;
  if (t0 >= n_e) return;
  int i0 = ix * 128;

  int tid = threadIdx.x;
  int r2 = tid >> 2;                           // row within 64-row half
  // chunk-XOR pre-swizzle: LDS[r][c] holds logical chunk c ^ (r&3); read applies same XOR.
  int sseg = (((tid & 3) ^ (r2 & 3)) * 8);     // elements (8 bf16 = 16B)

  int sr0 = t0 + r2;       if (sr0 >= n_e) sr0 = n_e - 1;
  int sr1 = t0 + 64 + r2;  if (sr1 >= n_e) sr1 = n_e - 1;
  int tok0 = list_tok[nbase + sr0] >> 1;
  int tok1 = list_tok[nbase + sr1] >> 1;
  const char* gA0  = (const char*)(xb + (size_t)tok0 * H_DIM + sseg);
  const char* gA1  = (const char*)(xb + (size_t)tok1 * H_DIM + sseg);
  const char* gB1a = (const char*)(w1t + ((size_t)e * I_DIM + i0 + r2) * H_DIM + sseg);
  const char* gB1b = (const char*)(w1t + ((size_t)e * I_DIM + i0 + 64 + r2) * H_DIM + sseg);
  const char* gB3a = (const char*)(w3t + ((size_t)e * I_DIM + i0 + r2) * H_DIM + sseg);
  const char* gB3b = (const char*)(w3t + ((size_t)e * I_DIM + i0 + 64 + r2) * H_DIM + sseg);

  // per-buffer 24KB: A [0,8K) rows0-127, B1 [8K,16K), B3 [16K,24K); buf1 at +24K
#define STAGE1(buf, kb) do {                              \
    gld16(gA0  + (kb) * 2, (buf) + tid * 16);             \
    gld16(gA1  + (kb) * 2, (buf) + 4096  + tid * 16);     \
    gld16(gB1a + (kb) * 2, (buf) + 8192  + tid * 16);     \
    gld16(gB1b + (kb) * 2, (buf) + 12288 + tid * 16);     \
    gld16(gB3a + (kb) * 2, (buf) + 16384 + tid * 16);     \
    gld16(gB3b + (kb) * 2, (buf) + 20480 + tid * 16);     \
  } while (0)

  int w = tid >> 6, lane = tid & 63, lm = lane & 15, lq = lane >> 4;
  int wm = w & 1, wn = w >> 1;
  int colx = (lq ^ (lm & 3)) * 16;             // swizzled 16B chunk within 64B row
  int rA = (wm * 64 + lm) * 64 + colx;         // + i*1024 for row block i
  int rB = (wn * 64 + lm) * 64 + colx;

  f32x4 acc1[4][4], acc3[4][4];
#pragma unroll
  for (int i = 0; i < 4; ++i)
#pragma unroll
    for (int j = 0; j < 4; ++j) { acc1[i][j] = (f32x4){0,0,0,0}; acc3[i][j] = (f32x4){0,0,0,0}; }

  STAGE1(smem, 0);
  __syncthreads();                              // vmcnt(0) drain: buf0 ready
  for (int kb = 0; kb < H_DIM; kb += 32) {
    char* cur = smem + (((kb >> 5) & 1) ? 24576 : 0);
    char* nxt = smem + (((kb >> 5) & 1) ? 0 : 24576);
    if (kb + 32 < H_DIM) STAGE1(nxt, kb + 32);  // issue-early: overlaps ds_read+MFMA
    bf16x8 a[4], b1[4], b3[4];
#pragma unroll
    for (int i = 0; i < 4; ++i)
      a[i] = *(const bf16x8*)(cur + rA + i * 1024);
#pragma unroll
    for (int j = 0; j < 4; ++j) {
      b1[j] = *(const bf16x8*)(cur + 8192  + rB + j * 1024);
      b3[j] = *(const bf16x8*)(cur + 16384 + rB + j * 1024);
    }
#pragma unroll
    for (int i = 0; i < 4; ++i)
#pragma unroll
      for (int j = 0; j < 4; ++j) {
        acc1[i][j] = __builtin_amdgcn_mfma_f32_16x16x32_bf16(a[i], b1[j], acc1[i][j], 0, 0, 0);
        acc3[i][j] = __builtin_amdgcn_mfma_f32_16x16x32_bf16(a[i], b3[j], acc3[i][j], 0, 0, 0);
      }
    __syncthreads();                            // drains next-tile loads + read fence
  }
#undef STAGE1

#pragma unroll
  for (int i = 0; i < 4; ++i) {
#pragma unroll
    for (int rr = 0; rr < 4; ++rr) {
      int slot = t0 + wm * 64 + i * 16 + lq * 4 + rr;
      if (slot < n_e) {
        unsigned short* orow = hbuf + (size_t)(nbase + slot) * I_DIM + i0 + wn * 64 + lm;
#pragma unroll
        for (int j = 0; j < 4; ++j) {
          float g = acc1[i][j][rr], u = acc3[i][j][rr];
          float hv = (g / (1.f + __expf(-g))) * u;
          orow[j * 16] = f2bf(hv);
        }
      }
    }
  }
}

// ---------------- GEMM2: 64 slots x 128 H, BK=32, split-K=2, 2-phase dbuf, swizzle ----------------
__global__ __launch_bounds__(256, 4) void gemm2(
    const unsigned short* __restrict__ hbuf,
    const unsigned short* __restrict__ w2t,
    const int* __restrict__ counts,
    const int* __restrict__ list_tok,
    const float* __restrict__ list_w,
    float* __restrict__ partial)
{
  __shared__ __align__(16) char smem[24576];   // 2 x 12KB
  int e = blockIdx.z;
  int nbase = 0;
#pragma unroll
  for (int i = 0; i < 8; ++i) if (i < e) nbase += counts[i];
  int n_e = counts[e];
  int ts = blockIdx.y >> 1, kh = blockIdx.y & 1;
  int t0 = ts * 64;
  if (t0 >= n_e) return;
  int h0 = blockIdx.x * 128;
  int k0 = kh * (I_DIM / 2);

  int tid = threadIdx.x;
  int r2 = tid >> 2;
  int sseg = (((tid & 3) ^ (r2 & 3)) * 8);

  int sr = t0 + r2; if (sr >= n_e) sr = n_e - 1;
  const char* gA  = (const char*)(hbuf + (size_t)(nbase + sr) * I_DIM + k0 + sseg);
  const char* gB0 = (const char*)(w2t + ((size_t)e * H_DIM + h0 + r2) * I_DIM + k0 + sseg);
  const char* gB1 = (const char*)(w2t + ((size_t)e * H_DIM + h0 + 64 + r2) * I_DIM + k0 + sseg);

  // per-buffer 12KB: A [0,4K) 64 slot-rows, B [4K,12K) 128 h-rows; buf1 at +12K
#define STAGE2(buf, kb) do {                              \
    gld16(gA  + (kb) * 2, (buf) + tid * 16);              \
    gld16(gB0 + (kb) * 2, (buf) + 4096 + tid * 16);       \
    gld16(gB1 + (kb) * 2, (buf) + 8192 + tid * 16);       \
  } while (0)

  int w = tid >> 6, lane = tid & 63, lm = lane & 15, lq = lane >> 4;
  int wm = w & 1, wn = w >> 1;
  int colx = (lq ^ (lm & 3)) * 16;
  int rA = (wm * 32 + lm) * 64 + colx;
  int rB = (wn * 64 + lm) * 64 + colx;

  f32x4 acc[2][4];
#pragma unroll
  for (int i = 0; i < 2; ++i)
#pragma unroll
    for (int j = 0; j < 4; ++j) acc[i][j] = (f32x4){0,0,0,0};

  STAGE2(smem, 0);
  __syncthreads();
  for (int kb = 0; kb < I_DIM / 2; kb += 32) {
    char* cur = smem + (((kb >> 5) & 1) ? 12288 : 0);
    char* nxt = smem + (((kb >> 5) & 1) ? 0 : 12288);
    if (kb + 32 < I_DIM / 2) STAGE2(nxt, kb + 32);
    bf16x8 a[2], b[4];
#pragma unroll
    for (int i = 0; i < 2; ++i)
      a[i] = *(const bf16x8*)(cur + rA + i * 1024);
#pragma unroll
    for (int j = 0; j < 4; ++j)
      b[j] = *(const bf16x8*)(cur + 4096 + rB + j * 1024);
#pragma unroll
    for (int i = 0; i < 2; ++i)
#pragma unroll
      for (int j = 0; j < 4; ++j)
        acc[i][j] = __builtin_amdgcn_mfma_f32_16x16x32_bf16(a[i], b[j], acc[i][j], 0, 0, 0);
    __syncthreads();
  }
#undef STAGE2

  int entv[2][4]; float wtv[2][4];
#pragma unroll
  for (int i = 0; i < 2; ++i)
#pragma unroll
    for (int rr = 0; rr < 4; ++rr) {
      int slot = t0 + wm * 32 + i * 16 + lq * 4 + rr;
      if (slot < n_e) { entv[i][rr] = list_tok[nbase + slot]; wtv[i][rr] = list_w[nbase + slot]; }
      else entv[i][rr] = -1;
    }
#pragma unroll
  for (int i = 0; i < 2; ++i)
#pragma unroll
    for (int j = 0; j < 4; ++j)
#pragma unroll
      for (int rr = 0; rr < 4; ++rr) {
        if (entv[i][rr] >= 0) {
          int t = entv[i][rr] >> 1, kk = entv[i][rr] & 1;
          int plane = kh * 2 + kk;
          partial[((size_t)plane * T_TOK + t) * H_DIM + h0 + wn * 64 + j * 16 + lm] =
              acc[i][j][rr] * wtv[i][rr];
        }
      }
}

// ---------------- out = sum of 4 partial planes ----------------
__global__ __launch_bounds__(256) void combine4(const float* __restrict__ partial,
                                                float* __restrict__ out)
{
  const size_t P = (size_t)T_TOK * H_DIM;
  size_t i = (size_t)(blockIdx.x * 256 + threadIdx.x) * 4;
  float4 a = *(const float4*)(partial + i);
  float4 b = *(const float4*)(partial + P + i);
  float4 c = *(const float4*)(partial + 2 * P + i);
  float4 d = *(const float4*)(partial + 3 * P + i);
  float4 o;
  o.x = a.x + b.x + c.x + d.x;
  o.y = a.y + b.y + c.y + d.y;
  o.z = a.z + b.z + c.z + d.z;
  o.w = a.w + b.w + c.w + d.w;
  *(float4*)(out + i) = o;
}

extern "C" void kernel_launch(void* const* d_in, const int* in_sizes, int n_in,
                              void* d_out, int out_size, void* d_ws, size_t ws_size,
                              hipStream_t stream) {
  const float* x  = (const float*)d_in[0];
  const float* gw = (const float*)d_in[1];
  const float* gb = (const float*)d_in[2];
  const float* w1 = (const float*)d_in[3];
  const float* w3 = (const float*)d_in[4];
  const float* w2 = (const float*)d_in[5];
  float* out = (float*)d_out;

  char* ws = (char*)d_ws;
  int*   counts   = (int*)(ws);            // 8 ints
  int*   rec_e    = (int*)(ws + 128);      // 4096 ints
  float* rec_w    = (float*)(ws + 16512);  // 4096 floats
  int*   list_tok = (int*)(ws + 32896);    // 4096 ints
  float* list_w   = (float*)(ws + 49280);  // 4096 floats
  const size_t MB = 1024ull * 1024ull;
  unsigned short* xb   = (unsigned short*)(ws + 1 * MB);    // 4 MB
  unsigned short* w1t  = (unsigned short*)(ws + 5 * MB);    // 32 MB  [E][I][H]
  float* partial       = (float*)(ws + 5 * MB);             // 32 MB  [4][T][H] (aliases w1t; dead after gemm1)
  unsigned short* w3t  = (unsigned short*)(ws + 37 * MB);   // 32 MB  [E][I][H]
  unsigned short* w2t  = (unsigned short*)(ws + 69 * MB);   // 32 MB  [E][H][I]
  unsigned short* hbuf = (unsigned short*)(ws + 101 * MB);  // 16 MB  [4096][I]

  gate_t13<<<2048, 256, 0, stream>>>(x, gw, gb, rec_e, rec_w, xb,
                                     w1, w3, w1t, w3t, w2, w2t);
  route8<<<8, 256, 0, stream>>>(rec_e, rec_w, counts, list_tok, list_w);
  gemm1<<<4096, 256, 0, stream>>>(xb, w1t, w3t, counts, list_tok, hbuf);
  gemm2<<<dim3(H_DIM / 128, 128, E_NUM), 256, 0, stream>>>(hbuf, w2t, counts, list_tok, list_w, partial);
  combine4<<<(T_TOK * H_DIM) / (256 * 4), 256, 0, stream>>>(partial, out);
}

// Round 7
// 364.811 us; speedup vs baseline: 1.2817x; 1.2817x over previous
//
#include <hip/hip_runtime.h>
#include <hip/hip_bf16.h>
#include <math.h>

typedef __attribute__((ext_vector_type(4))) float f32x4;
typedef __attribute__((ext_vector_type(8))) short bf16x8;

#define T_TOK 2048
#define H_DIM 1024
#define I_DIM 2048
#define E_NUM 8

// RNE float -> bf16
__device__ inline unsigned short f2bf(float f) {
  union { float f; unsigned int u; } v; v.f = f;
  unsigned int r = v.u + 0x7fffu + ((v.u >> 16) & 1u);
  return (unsigned short)(r >> 16);
}
__device__ inline unsigned int pack2(float a, float b) {
  return (unsigned int)f2bf(a) | ((unsigned int)f2bf(b) << 16);
}

// async global->LDS, 16 bytes per lane
__device__ inline void gld16(const void* g, void* l) {
  __builtin_amdgcn_global_load_lds((const __attribute__((address_space(1))) void*)g,
                                   (__attribute__((address_space(3))) void*)l, 16, 0, 0);
}

// ---------------- pipelined 4x(paired 64x64) fp32 [R][C] -> bf16 [C][R] transpose ----------
// One block handles rows [rpg*512, rpg*512+512) x cols [ct*64, ct*64+64), as 4 sequential
// 128x64 tile-pairs. Tile t+1's 8 float4 loads are issued while tile t is in its LDS/store
// phase, so HBM latency hides under the store phase instead of serializing per tile.
__device__ inline void transpose_quad(const float* __restrict__ ip, unsigned short* __restrict__ op,
                                      int R, int C, int rpg, int ct, char* smem)
{
  unsigned short (*tl)[66] = (unsigned short (*)[66])smem;   // [2*64 cols][64 rows + pad2]
  int c0 = ct * 64;
  int tid = threadIdx.x;
  int rq = (tid >> 4) * 4;        // 4 consecutive rows within 64-row tile
  int c4 = (tid & 15) * 4;        // 4 consecutive cols
  int cs = tid >> 3, r8 = (tid & 7) * 8;   // store-phase indices

  float4 v[8];
  {
    int r0 = rpg * 512;
    const float* b0 = ip + (size_t)(r0 + rq) * C + c0 + c4;
    const float* b1 = b0 + (size_t)64 * C;
#pragma unroll
    for (int q = 0; q < 4; ++q) { v[q] = *(const float4*)(b0 + q * C); v[4 + q] = *(const float4*)(b1 + q * C); }
  }
#pragma unroll
  for (int t = 0; t < 4; ++t) {
    const float* f = (const float*)v;
#pragma unroll
    for (int j = 0; j < 4; ++j) {
      *(unsigned int*)&tl[c4 + j][rq]          = pack2(f[0 * 4 + j], f[1 * 4 + j]);
      *(unsigned int*)&tl[c4 + j][rq + 2]      = pack2(f[2 * 4 + j], f[3 * 4 + j]);
      *(unsigned int*)&tl[64 + c4 + j][rq]     = pack2(f[4 * 4 + j], f[5 * 4 + j]);
      *(unsigned int*)&tl[64 + c4 + j][rq + 2] = pack2(f[6 * 4 + j], f[7 * 4 + j]);
    }
    if (t < 3) {                 // issue next tile's loads; in flight across both barriers
      int rn = rpg * 512 + (t + 1) * 128;
      const float* n0 = ip + (size_t)(rn + rq) * C + c0 + c4;
      const float* n1 = n0 + (size_t)64 * C;
#pragma unroll
      for (int q = 0; q < 4; ++q) { v[q] = *(const float4*)(n0 + q * C); v[4 + q] = *(const float4*)(n1 + q * C); }
    }
    __syncthreads();
    int r0t = rpg * 512 + t * 128;
#pragma unroll
    for (int it = 0; it < 2; ++it) {
      int cc = cs + it * 32;
#pragma unroll
      for (int p = 0; p < 2; ++p) {
        uint4 o;
        o.x = *(const unsigned int*)&tl[p * 64 + cc][r8];
        o.y = *(const unsigned int*)&tl[p * 64 + cc][r8 + 2];
        o.z = *(const unsigned int*)&tl[p * 64 + cc][r8 + 4];
        o.w = *(const unsigned int*)&tl[p * 64 + cc][r8 + 6];
        *(uint4*)(op + (size_t)(c0 + cc) * R + r0t + p * 64 + r8) = o;
      }
    }
    __syncthreads();
  }
}

// ---------------- kernel 1: gate (+x cast) fused with transpose of w1,w3,w2 ----------------
// blocks [0,512): gate; [512,1536): w1/w3 quad-tiles; [1536,2048): w2 quad-tiles
__global__ __launch_bounds__(256) void gate_t13(
    const float* __restrict__ x, const float* __restrict__ gw, const float* __restrict__ gb,
    int* __restrict__ rec_e, float* __restrict__ rec_w, unsigned short* __restrict__ xb,
    const float* __restrict__ w1, const float* __restrict__ w3,
    unsigned short* __restrict__ w1t, unsigned short* __restrict__ w3t,
    const float* __restrict__ w2, unsigned short* __restrict__ w2t)
{
  __shared__ __align__(16) char smem[128 * 66 * 2];
  int bx = blockIdx.x;
  if (bx >= 1536) {
    int idx = bx - 1536;       // w2: [E][I][H] -> w2t [E][H][I]
    int e = idx >> 6;          // 0..7
    int sub = idx & 63;
    int rpg = sub & 3;         // R = I_DIM -> 4 quad-groups
    int ct = sub >> 2;         // C = H_DIM -> 16 col tiles
    const float* ip = w2 + (size_t)e * ((size_t)H_DIM * I_DIM);
    unsigned short* op = w2t + (size_t)e * ((size_t)H_DIM * I_DIM);
    transpose_quad(ip, op, I_DIM, H_DIM, rpg, ct, smem);
    return;
  }
  if (bx >= 512) {
    int idx = bx - 512;
    int m = idx >> 6;          // 0..15
    int sub = idx & 63;
    int rpg = sub & 1;         // R = H_DIM -> 2 quad-groups
    int ct = sub >> 1;         // C = I_DIM -> 32 col tiles
    const float* ip = (m < 8 ? w1 : w3) + (size_t)(m & 7) * ((size_t)H_DIM * I_DIM);
    unsigned short* op = (m < 8 ? w1t : w3t) + (size_t)(m & 7) * ((size_t)H_DIM * I_DIM);
    transpose_quad(ip, op, H_DIM, I_DIM, rpg, ct, smem);
    return;
  }
  int wv = threadIdx.x >> 6, lane = threadIdx.x & 63;
  int t = bx * 4 + wv;
  const float* xr = x + (size_t)t * H_DIM;
  unsigned short* xo = xb + (size_t)t * H_DIM;
  float acc[8];
#pragma unroll
  for (int e = 0; e < 8; ++e) acc[e] = 0.f;
  for (int i = 0; i < H_DIM / 64; ++i) {
    int h = i * 64 + lane;
    float xv = xr[h];
    xo[h] = f2bf(xv);
    const float4* g = (const float4*)(gw + (size_t)h * 8);
    float4 g0 = g[0], g1 = g[1];
    acc[0] += xv * g0.x; acc[1] += xv * g0.y; acc[2] += xv * g0.z; acc[3] += xv * g0.w;
    acc[4] += xv * g1.x; acc[5] += xv * g1.y; acc[6] += xv * g1.z; acc[7] += xv * g1.w;
  }
#pragma unroll
  for (int s = 1; s < 64; s <<= 1) {
#pragma unroll
    for (int e = 0; e < 8; ++e) acc[e] += __shfl_xor(acc[e], s);
  }
  if (lane == 0) {
    float l[8];
#pragma unroll
    for (int e = 0; e < 8; ++e) l[e] = acc[e] + gb[e];
    int e0 = 0;
    for (int e = 1; e < 8; ++e) if (l[e] > l[e0]) e0 = e;
    int e1 = (e0 == 0) ? 1 : 0;
    for (int e = 0; e < 8; ++e) if (e != e0 && l[e] > l[e1]) e1 = e;
    float w0 = 1.f / (1.f + expf(l[e1] - l[e0]));
    rec_e[t * 2]     = e0; rec_e[t * 2 + 1] = e1;
    rec_w[t * 2]     = w0; rec_w[t * 2 + 1] = 1.f - w0;
  }
}

// ---------------- routing: 8 blocks, one per expert ----------------
__global__ __launch_bounds__(256) void route8(
    const int* __restrict__ rec_e, const float* __restrict__ rec_w,
    int* __restrict__ counts_g, int* __restrict__ list_tok, float* __restrict__ list_w)
{
  __shared__ int cnt[8];
  __shared__ int fill;
  int e = blockIdx.x;
  int tid = threadIdx.x;
  if (tid < 8) cnt[tid] = 0;
  if (tid == 0) fill = 0;
  __syncthreads();
  int e_loc[16];
  int c_loc[8];
#pragma unroll
  for (int k = 0; k < 8; ++k) c_loc[k] = 0;
#pragma unroll
  for (int it = 0; it < 16; ++it) {
    e_loc[it] = rec_e[it * 256 + tid] & 7;
    c_loc[e_loc[it]]++;
  }
#pragma unroll
  for (int k = 0; k < 8; ++k) if (c_loc[k]) atomicAdd(&cnt[k], c_loc[k]);
  __syncthreads();
  if (e == 0 && tid < 8) counts_g[tid] = cnt[tid];
  int base = 0;
#pragma unroll
  for (int k = 0; k < 8; ++k) if (k < e) base += cnt[k];
#pragma unroll
  for (int it = 0; it < 16; ++it) {
    if (e_loc[it] == e) {
      int i = it * 256 + tid;
      int pos = atomicAdd(&fill, 1);
      list_tok[base + pos] = i;            // i = (t<<1)|k
      list_w[base + pos]   = rec_w[i];
    }
  }
}

// ---------------- gemm1: 128x128 dual (B1,B3), BK=32, 2-phase dbuf, swizzled LDS ----------------
__global__ __launch_bounds__(256, 2) void gemm1(
    const unsigned short* __restrict__ xb,
    const unsigned short* __restrict__ w1t,
    const unsigned short* __restrict__ w3t,
    const int* __restrict__ counts,
    const int* __restrict__ list_tok,
    unsigned short* __restrict__ hbuf)
{
  __shared__ __align__(16) char smem[49152];
  int bx = blockIdx.x;
  int e = bx >> 9;
  int y = (bx >> 4) & 31;
  int ix = bx & 15;
  int nbase = 0;
#pragma unroll
  for (int i = 0; i < 8; ++i) if (i < e) nbase += counts[i];
  int n_e = counts[e];
  int t0 = y * 128;
  if (t0 >= n_e) return;
  int i0 = ix * 128;

  int tid = threadIdx.x;
  int r2 = tid >> 2;                           // row within 64-row half
  // chunk-XOR pre-swizzle: LDS[r][c] holds logical chunk c ^ (r&3); read applies same XOR.
  int sseg = (((tid & 3) ^ (r2 & 3)) * 8);     // elements (8 bf16 = 16B)

  int sr0 = t0 + r2;       if (sr0 >= n_e) sr0 = n_e - 1;
  int sr1 = t0 + 64 + r2;  if (sr1 >= n_e) sr1 = n_e - 1;
  int tok0 = list_tok[nbase + sr0] >> 1;
  int tok1 = list_tok[nbase + sr1] >> 1;
  const char* gA0  = (const char*)(xb + (size_t)tok0 * H_DIM + sseg);
  const char* gA1  = (const char*)(xb + (size_t)tok1 * H_DIM + sseg);
  const char* gB1a = (const char*)(w1t + ((size_t)e * I_DIM + i0 + r2) * H_DIM + sseg);
  const char* gB1b = (const char*)(w1t + ((size_t)e * I_DIM + i0 + 64 + r2) * H_DIM + sseg);
  const char* gB3a = (const char*)(w3t + ((size_t)e * I_DIM + i0 + r2) * H_DIM + sseg);
  const char* gB3b = (const char*)(w3t + ((size_t)e * I_DIM + i0 + 64 + r2) * H_DIM + sseg);

  // per-buffer 24KB: A [0,8K) rows0-127, B1 [8K,16K), B3 [16K,24K); buf1 at +24K
#define STAGE1(buf, kb) do {                              \
    gld16(gA0  + (kb) * 2, (buf) + tid * 16);             \
    gld16(gA1  + (kb) * 2, (buf) + 4096  + tid * 16);     \
    gld16(gB1a + (kb) * 2, (buf) + 8192  + tid * 16);     \
    gld16(gB1b + (kb) * 2, (buf) + 12288 + tid * 16);     \
    gld16(gB3a + (kb) * 2, (buf) + 16384 + tid * 16);     \
    gld16(gB3b + (kb) * 2, (buf) + 20480 + tid * 16);     \
  } while (0)

  int w = tid >> 6, lane = tid & 63, lm = lane & 15, lq = lane >> 4;
  int wm = w & 1, wn = w >> 1;
  int colx = (lq ^ (lm & 3)) * 16;             // swizzled 16B chunk within 64B row
  int rA = (wm * 64 + lm) * 64 + colx;         // + i*1024 for row block i
  int rB = (wn * 64 + lm) * 64 + colx;

  f32x4 acc1[4][4], acc3[4][4];
#pragma unroll
  for (int i = 0; i < 4; ++i)
#pragma unroll
    for (int j = 0; j < 4; ++j) { acc1[i][j] = (f32x4){0,0,0,0}; acc3[i][j] = (f32x4){0,0,0,0}; }

  STAGE1(smem, 0);
  __syncthreads();                              // vmcnt(0) drain: buf0 ready
  for (int kb = 0; kb < H_DIM; kb += 32) {
    char* cur = smem + (((kb >> 5) & 1) ? 24576 : 0);
    char* nxt = smem + (((kb >> 5) & 1) ? 0 : 24576);
    if (kb + 32 < H_DIM) STAGE1(nxt, kb + 32);  // issue-early: overlaps ds_read+MFMA
    bf16x8 a[4], b1[4], b3[4];
#pragma unroll
    for (int i = 0; i < 4; ++i)
      a[i] = *(const bf16x8*)(cur + rA + i * 1024);
#pragma unroll
    for (int j = 0; j < 4; ++j) {
      b1[j] = *(const bf16x8*)(cur + 8192  + rB + j * 1024);
      b3[j] = *(const bf16x8*)(cur + 16384 + rB + j * 1024);
    }
#pragma unroll
    for (int i = 0; i < 4; ++i)
#pragma unroll
      for (int j = 0; j < 4; ++j) {
        acc1[i][j] = __builtin_amdgcn_mfma_f32_16x16x32_bf16(a[i], b1[j], acc1[i][j], 0, 0, 0);
        acc3[i][j] = __builtin_amdgcn_mfma_f32_16x16x32_bf16(a[i], b3[j], acc3[i][j], 0, 0, 0);
      }
    __syncthreads();                            // drains next-tile loads + read fence
  }
#undef STAGE1

#pragma unroll
  for (int i = 0; i < 4; ++i) {
#pragma unroll
    for (int rr = 0; rr < 4; ++rr) {
      int slot = t0 + wm * 64 + i * 16 + lq * 4 + rr;
      if (slot < n_e) {
        unsigned short* orow = hbuf + (size_t)(nbase + slot) * I_DIM + i0 + wn * 64 + lm;
#pragma unroll
        for (int j = 0; j < 4; ++j) {
          float g = acc1[i][j][rr], u = acc3[i][j][rr];
          float hv = (g / (1.f + __expf(-g))) * u;
          orow[j * 16] = f2bf(hv);
        }
      }
    }
  }
}

// ---------------- GEMM2: 64 slots x 128 H, BK=32, split-K=2, 2-phase dbuf, swizzle ----------------
__global__ __launch_bounds__(256, 4) void gemm2(
    const unsigned short* __restrict__ hbuf,
    const unsigned short* __restrict__ w2t,
    const int* __restrict__ counts,
    const int* __restrict__ list_tok,
    const float* __restrict__ list_w,
    float* __restrict__ partial)
{
  __shared__ __align__(16) char smem[24576];   // 2 x 12KB
  int e = blockIdx.z;
  int nbase = 0;
#pragma unroll
  for (int i = 0; i < 8; ++i) if (i < e) nbase += counts[i];
  int n_e = counts[e];
  int ts = blockIdx.y >> 1, kh = blockIdx.y & 1;
  int t0 = ts * 64;
  if (t0 >= n_e) return;
  int h0 = blockIdx.x * 128;
  int k0 = kh * (I_DIM / 2);

  int tid = threadIdx.x;
  int r2 = tid >> 2;
  int sseg = (((tid & 3) ^ (r2 & 3)) * 8);

  int sr = t0 + r2; if (sr >= n_e) sr = n_e - 1;
  const char* gA  = (const char*)(hbuf + (size_t)(nbase + sr) * I_DIM + k0 + sseg);
  const char* gB0 = (const char*)(w2t + ((size_t)e * H_DIM + h0 + r2) * I_DIM + k0 + sseg);
  const char* gB1 = (const char*)(w2t + ((size_t)e * H_DIM + h0 + 64 + r2) * I_DIM + k0 + sseg);

  // per-buffer 12KB: A [0,4K) 64 slot-rows, B [4K,12K) 128 h-rows; buf1 at +12K
#define STAGE2(buf, kb) do {                              \
    gld16(gA  + (kb) * 2, (buf) + tid * 16);              \
    gld16(gB0 + (kb) * 2, (buf) + 4096 + tid * 16);       \
    gld16(gB1 + (kb) * 2, (buf) + 8192 + tid * 16);       \
  } while (0)

  int w = tid >> 6, lane = tid & 63, lm = lane & 15, lq = lane >> 4;
  int wm = w & 1, wn = w >> 1;
  int colx = (lq ^ (lm & 3)) * 16;
  int rA = (wm * 32 + lm) * 64 + colx;
  int rB = (wn * 64 + lm) * 64 + colx;

  f32x4 acc[2][4];
#pragma unroll
  for (int i = 0; i < 2; ++i)
#pragma unroll
    for (int j = 0; j < 4; ++j) acc[i][j] = (f32x4){0,0,0,0};

  STAGE2(smem, 0);
  __syncthreads();
  for (int kb = 0; kb < I_DIM / 2; kb += 32) {
    char* cur = smem + (((kb >> 5) & 1) ? 12288 : 0);
    char* nxt = smem + (((kb >> 5) & 1) ? 0 : 12288);
    if (kb + 32 < I_DIM / 2) STAGE2(nxt, kb + 32);
    bf16x8 a[2], b[4];
#pragma unroll
    for (int i = 0; i < 2; ++i)
      a[i] = *(const bf16x8*)(cur + rA + i * 1024);
#pragma unroll
    for (int j = 0; j < 4; ++j)
      b[j] = *(const bf16x8*)(cur + 4096 + rB + j * 1024);
#pragma unroll
    for (int i = 0; i < 2; ++i)
#pragma unroll
      for (int j = 0; j < 4; ++j)
        acc[i][j] = __builtin_amdgcn_mfma_f32_16x16x32_bf16(a[i], b[j], acc[i][j], 0, 0, 0);
    __syncthreads();
  }
#undef STAGE2

  int entv[2][4]; float wtv[2][4];
#pragma unroll
  for (int i = 0; i < 2; ++i)
#pragma unroll
    for (int rr = 0; rr < 4; ++rr) {
      int slot = t0 + wm * 32 + i * 16 + lq * 4 + rr;
      if (slot < n_e) { entv[i][rr] = list_tok[nbase + slot]; wtv[i][rr] = list_w[nbase + slot]; }
      else entv[i][rr] = -1;
    }
#pragma unroll
  for (int i = 0; i < 2; ++i)
#pragma unroll
    for (int j = 0; j < 4; ++j)
#pragma unroll
      for (int rr = 0; rr < 4; ++rr) {
        if (entv[i][rr] >= 0) {
          int t = entv[i][rr] >> 1, kk = entv[i][rr] & 1;
          int plane = kh * 2 + kk;
          partial[((size_t)plane * T_TOK + t) * H_DIM + h0 + wn * 64 + j * 16 + lm] =
              acc[i][j][rr] * wtv[i][rr];
        }
      }
}

// ---------------- out = sum of 4 partial planes ----------------
__global__ __launch_bounds__(256) void combine4(const float* __restrict__ partial,
                                                float* __restrict__ out)
{
  const size_t P = (size_t)T_TOK * H_DIM;
  size_t i = (size_t)(blockIdx.x * 256 + threadIdx.x) * 4;
  float4 a = *(const float4*)(partial + i);
  float4 b = *(const float4*)(partial + P + i);
  float4 c = *(const float4*)(partial + 2 * P + i);
  float4 d = *(const float4*)(partial + 3 * P + i);
  float4 o;
  o.x = a.x + b.x + c.x + d.x;
  o.y = a.y + b.y + c.y + d.y;
  o.z = a.z + b.z + c.z + d.z;
  o.w = a.w + b.w + c.w + d.w;
  *(float4*)(out + i) = o;
}

extern "C" void kernel_launch(void* const* d_in, const int* in_sizes, int n_in,
                              void* d_out, int out_size, void* d_ws, size_t ws_size,
                              hipStream_t stream) {
  const float* x  = (const float*)d_in[0];
  const float* gw = (const float*)d_in[1];
  const float* gb = (const float*)d_in[2];
  const float* w1 = (const float*)d_in[3];
  const float* w3 = (const float*)d_in[4];
  const float* w2 = (const float*)d_in[5];
  float* out = (float*)d_out;

  char* ws = (char*)d_ws;
  int*   counts   = (int*)(ws);            // 8 ints
  int*   rec_e    = (int*)(ws + 128);      // 4096 ints
  float* rec_w    = (float*)(ws + 16512);  // 4096 floats
  int*   list_tok = (int*)(ws + 32896);    // 4096 ints
  float* list_w   = (float*)(ws + 49280);  // 4096 floats
  const size_t MB = 1024ull * 1024ull;
  unsigned short* xb   = (unsigned short*)(ws + 1 * MB);    // 4 MB
  unsigned short* w1t  = (unsigned short*)(ws + 5 * MB);    // 32 MB  [E][I][H]
  float* partial       = (float*)(ws + 5 * MB);             // 32 MB  [4][T][H] (aliases w1t; dead after gemm1)
  unsigned short* w3t  = (unsigned short*)(ws + 37 * MB);   // 32 MB  [E][I][H]
  unsigned short* w2t  = (unsigned short*)(ws + 69 * MB);   // 32 MB  [E][H][I]
  unsigned short* hbuf = (unsigned short*)(ws + 101 * MB);  // 16 MB  [4096][I]

  gate_t13<<<2048, 256, 0, stream>>>(x, gw, gb, rec_e, rec_w, xb,
                                     w1, w3, w1t, w3t, w2, w2t);
  route8<<<8, 256, 0, stream>>>(rec_e, rec_w, counts, list_tok, list_w);
  gemm1<<<4096, 256, 0, stream>>>(xb, w1t, w3t, counts, list_tok, hbuf);
  gemm2<<<dim3(H_DIM / 128, 128, E_NUM), 256, 0, stream>>>(hbuf, w2t, counts, list_tok, list_w, partial);
  combine4<<<(T_TOK * H_DIM) / (256 * 4), 256, 0, stream>>>(partial, out);
}

// Round 8
// 359.685 us; speedup vs baseline: 1.2999x; 1.0143x over previous
//
#include <hip/hip_runtime.h>
#include <hip/hip_bf16.h>
#include <math.h>

typedef __attribute__((ext_vector_type(4))) float f32x4;
typedef __attribute__((ext_vector_type(8))) short bf16x8;

#define T_TOK 2048
#define H_DIM 1024
#define I_DIM 2048
#define E_NUM 8

// RNE float -> bf16
__device__ inline unsigned short f2bf(float f) {
  union { float f; unsigned int u; } v; v.f = f;
  unsigned int r = v.u + 0x7fffu + ((v.u >> 16) & 1u);
  return (unsigned short)(r >> 16);
}
__device__ inline unsigned int pack2(float a, float b) {
  return (unsigned int)f2bf(a) | ((unsigned int)f2bf(b) << 16);
}

// async global->LDS, 16 bytes per lane
__device__ inline void gld16(const void* g, void* l) {
  __builtin_amdgcn_global_load_lds((const __attribute__((address_space(1))) void*)g,
                                   (__attribute__((address_space(3))) void*)l, 16, 0, 0);
}

// ---------------- 256x128 fp32 [R][C] -> bf16 [C][R] transpose, 512B chunks both sides ----
// Tile: input rows [rp*256, rp*256+256) x cols [ct*128, ct*128+128).
// Reads: 128 cols x 4B = 512B contiguous per row. Writes: 256 rows x 2B = 512B contiguous
// per output row. LDS [128 c][264 r] bf16 with r-XOR swizzle (r ^= 8*((c>>2)&7)) to break
// the 132-dword-stride bank alias in the pack phase while keeping 16B-aligned uint4 reads.
__device__ inline void transpose256(const float* __restrict__ ip, unsigned short* __restrict__ op,
                                    int R, int C, int rp, int ct, char* smem)
{
  unsigned short (*tl)[264] = (unsigned short (*)[264])smem;
  int r0 = rp * 256, c0 = ct * 128;
  int tid = threadIdx.x;
  int cg = tid & 31;            // col-group: 4 consecutive cols
  int rg = tid >> 5;            // row-group within phase: 4 consecutive rows
  int S = 8 * (cg & 7);         // r-swizzle for this thread's columns (c>>2 == cg)

  const float* base = ip + (size_t)(r0 + rg * 4) * C + c0 + cg * 4;
#pragma unroll
  for (int p = 0; p < 8; ++p) {
    const float* bp = base + (size_t)(p * 32) * C;   // 32 rows per phase
    float4 v0 = *(const float4*)(bp);
    float4 v1 = *(const float4*)(bp + C);
    float4 v2 = *(const float4*)(bp + 2 * C);
    float4 v3 = *(const float4*)(bp + 3 * C);
    int rr = p * 32 + rg * 4;                        // logical row within tile (even)
    int rph = rr ^ S;                                // physical row slot
#pragma unroll
    for (int j = 0; j < 4; ++j) {
      *(unsigned int*)&tl[cg * 4 + j][rph]     = pack2(v0[j], v1[j]);
      *(unsigned int*)&tl[cg * 4 + j][rph + 2] = pack2(v2[j], v3[j]);
    }
  }
  __syncthreads();
  // store: output row c gets 256 rows; 32 lanes x 16B = 512B contiguous per c
  int cs = tid >> 5;            // 0..7
  int rs = (tid & 31) * 8;      // logical 8-elem segment
#pragma unroll
  for (int cc = 0; cc < 16; ++cc) {
    int c = cc * 8 + cs;
    int Sc = 8 * ((c >> 2) & 7);
    uint4 o = *(const uint4*)&tl[c][rs ^ Sc];
    *(uint4*)(op + (size_t)(c0 + c) * R + r0 + rs) = o;
  }
}

// ---------------- kernel 1: gate (+x cast) fused with transpose of w1,w3,w2 ----------------
// blocks [0,512): gate; [512,1536): w1/w3 tiles; [1536,2048): w2 tiles
__global__ __launch_bounds__(256) void gate_t13(
    const float* __restrict__ x, const float* __restrict__ gw, const float* __restrict__ gb,
    int* __restrict__ rec_e, float* __restrict__ rec_w, unsigned short* __restrict__ xb,
    const float* __restrict__ w1, const float* __restrict__ w3,
    unsigned short* __restrict__ w1t, unsigned short* __restrict__ w3t,
    const float* __restrict__ w2, unsigned short* __restrict__ w2t)
{
  __shared__ __align__(16) char smem[128 * 264 * 2];
  int bx = blockIdx.x;
  if (bx >= 1536) {
    int idx = bx - 1536;       // w2: [I][H] -> w2t [H][I], per expert
    int e = idx >> 6;          // 0..7
    int sub = idx & 63;
    int rp = sub & 7;          // R = I_DIM -> 8 row-tiles of 256
    int ct = sub >> 3;         // C = H_DIM -> 8 col-tiles of 128
    const float* ip = w2 + (size_t)e * ((size_t)H_DIM * I_DIM);
    unsigned short* op = w2t + (size_t)e * ((size_t)H_DIM * I_DIM);
    transpose256(ip, op, I_DIM, H_DIM, rp, ct, smem);
    return;
  }
  if (bx >= 512) {
    int idx = bx - 512;        // w1/w3: [H][I] -> [I][H], per expert
    int m = idx >> 6;          // 0..15
    int sub = idx & 63;
    int rp = sub & 3;          // R = H_DIM -> 4 row-tiles of 256
    int ct = sub >> 2;         // C = I_DIM -> 16 col-tiles of 128
    const float* ip = (m < 8 ? w1 : w3) + (size_t)(m & 7) * ((size_t)H_DIM * I_DIM);
    unsigned short* op = (m < 8 ? w1t : w3t) + (size_t)(m & 7) * ((size_t)H_DIM * I_DIM);
    transpose256(ip, op, H_DIM, I_DIM, rp, ct, smem);
    return;
  }
  int wv = threadIdx.x >> 6, lane = threadIdx.x & 63;
  int t = bx * 4 + wv;
  const float* xr = x + (size_t)t * H_DIM;
  unsigned short* xo = xb + (size_t)t * H_DIM;
  float acc[8];
#pragma unroll
  for (int e = 0; e < 8; ++e) acc[e] = 0.f;
  for (int i = 0; i < H_DIM / 64; ++i) {
    int h = i * 64 + lane;
    float xv = xr[h];
    xo[h] = f2bf(xv);
    const float4* g = (const float4*)(gw + (size_t)h * 8);
    float4 g0 = g[0], g1 = g[1];
    acc[0] += xv * g0.x; acc[1] += xv * g0.y; acc[2] += xv * g0.z; acc[3] += xv * g0.w;
    acc[4] += xv * g1.x; acc[5] += xv * g1.y; acc[6] += xv * g1.z; acc[7] += xv * g1.w;
  }
#pragma unroll
  for (int s = 1; s < 64; s <<= 1) {
#pragma unroll
    for (int e = 0; e < 8; ++e) acc[e] += __shfl_xor(acc[e], s);
  }
  if (lane == 0) {
    float l[8];
#pragma unroll
    for (int e = 0; e < 8; ++e) l[e] = acc[e] + gb[e];
    int e0 = 0;
    for (int e = 1; e < 8; ++e) if (l[e] > l[e0]) e0 = e;
    int e1 = (e0 == 0) ? 1 : 0;
    for (int e = 0; e < 8; ++e) if (e != e0 && l[e] > l[e1]) e1 = e;
    float w0 = 1.f / (1.f + expf(l[e1] - l[e0]));
    rec_e[t * 2]     = e0; rec_e[t * 2 + 1] = e1;
    rec_w[t * 2]     = w0; rec_w[t * 2 + 1] = 1.f - w0;
  }
}

// ---------------- routing: 8 blocks, one per expert ----------------
__global__ __launch_bounds__(256) void route8(
    const int* __restrict__ rec_e, const float* __restrict__ rec_w,
    int* __restrict__ counts_g, int* __restrict__ list_tok, float* __restrict__ list_w)
{
  __shared__ int cnt[8];
  __shared__ int fill;
  int e = blockIdx.x;
  int tid = threadIdx.x;
  if (tid < 8) cnt[tid] = 0;
  if (tid == 0) fill = 0;
  __syncthreads();
  int e_loc[16];
  int c_loc[8];
#pragma unroll
  for (int k = 0; k < 8; ++k) c_loc[k] = 0;
#pragma unroll
  for (int it = 0; it < 16; ++it) {
    e_loc[it] = rec_e[it * 256 + tid] & 7;
    c_loc[e_loc[it]]++;
  }
#pragma unroll
  for (int k = 0; k < 8; ++k) if (c_loc[k]) atomicAdd(&cnt[k], c_loc[k]);
  __syncthreads();
  if (e == 0 && tid < 8) counts_g[tid] = cnt[tid];
  int base = 0;
#pragma unroll
  for (int k = 0; k < 8; ++k) if (k < e) base += cnt[k];
#pragma unroll
  for (int it = 0; it < 16; ++it) {
    if (e_loc[it] == e) {
      int i = it * 256 + tid;
      int pos = atomicAdd(&fill, 1);
      list_tok[base + pos] = i;            // i = (t<<1)|k
      list_w[base + pos]   = rec_w[i];
    }
  }
}

// ---------------- gemm1: 128x128 dual (B1,B3), BK=32, 2-phase dbuf, swizzled LDS ----------------
__global__ __launch_bounds__(256, 2) void gemm1(
    const unsigned short* __restrict__ xb,
    const unsigned short* __restrict__ w1t,
    const unsigned short* __restrict__ w3t,
    const int* __restrict__ counts,
    const int* __restrict__ list_tok,
    unsigned short* __restrict__ hbuf)
{
  __shared__ __align__(16) char smem[49152];
  int bx = blockIdx.x;
  int e = bx >> 9;
  int y = (bx >> 4) & 31;
  int ix = bx & 15;
  int nbase = 0;
#pragma unroll
  for (int i = 0; i < 8; ++i) if (i < e) nbase += counts[i];
  int n_e = counts[e];
  int t0 = y * 128;
  if (t0 >= n_e) return;
  int i0 = ix * 128;

  int tid = threadIdx.x;
  int r2 = tid >> 2;                           // row within 64-row half
  // chunk-XOR pre-swizzle: LDS[r][c] holds logical chunk c ^ (r&3); read applies same XOR.
  int sseg = (((tid & 3) ^ (r2 & 3)) * 8);     // elements (8 bf16 = 16B)

  int sr0 = t0 + r2;       if (sr0 >= n_e) sr0 = n_e - 1;
  int sr1 = t0 + 64 + r2;  if (sr1 >= n_e) sr1 = n_e - 1;
  int tok0 = list_tok[nbase + sr0] >> 1;
  int tok1 = list_tok[nbase + sr1] >> 1;
  const char* gA0  = (const char*)(xb + (size_t)tok0 * H_DIM + sseg);
  const char* gA1  = (const char*)(xb + (size_t)tok1 * H_DIM + sseg);
  const char* gB1a = (const char*)(w1t + ((size_t)e * I_DIM + i0 + r2) * H_DIM + sseg);
  const char* gB1b = (const char*)(w1t + ((size_t)e * I_DIM + i0 + 64 + r2) * H_DIM + sseg);
  const char* gB3a = (const char*)(w3t + ((size_t)e * I_DIM + i0 + r2) * H_DIM + sseg);
  const char* gB3b = (const char*)(w3t + ((size_t)e * I_DIM + i0 + 64 + r2) * H_DIM + sseg);

  // per-buffer 24KB: A [0,8K) rows0-127, B1 [8K,16K), B3 [16K,24K); buf1 at +24K
#define STAGE1(buf, kb) do {                              \
    gld16(gA0  + (kb) * 2, (buf) + tid * 16);             \
    gld16(gA1  + (kb) * 2, (buf) + 4096  + tid * 16);     \
    gld16(gB1a + (kb) * 2, (buf) + 8192  + tid * 16);     \
    gld16(gB1b + (kb) * 2, (buf) + 12288 + tid * 16);     \
    gld16(gB3a + (kb) * 2, (buf) + 16384 + tid * 16);     \
    gld16(gB3b + (kb) * 2, (buf) + 20480 + tid * 16);     \
  } while (0)

  int w = tid >> 6, lane = tid & 63, lm = lane & 15, lq = lane >> 4;
  int wm = w & 1, wn = w >> 1;
  int colx = (lq ^ (lm & 3)) * 16;             // swizzled 16B chunk within 64B row
  int rA = (wm * 64 + lm) * 64 + colx;         // + i*1024 for row block i
  int rB = (wn * 64 + lm) * 64 + colx;

  f32x4 acc1[4][4], acc3[4][4];
#pragma unroll
  for (int i = 0; i < 4; ++i)
#pragma unroll
    for (int j = 0; j < 4; ++j) { acc1[i][j] = (f32x4){0,0,0,0}; acc3[i][j] = (f32x4){0,0,0,0}; }

  STAGE1(smem, 0);
  __syncthreads();                              // vmcnt(0) drain: buf0 ready
  for (int kb = 0; kb < H_DIM; kb += 32) {
    char* cur = smem + (((kb >> 5) & 1) ? 24576 : 0);
    char* nxt = smem + (((kb >> 5) & 1) ? 0 : 24576);
    if (kb + 32 < H_DIM) STAGE1(nxt, kb + 32);  // issue-early: overlaps ds_read+MFMA
    bf16x8 a[4], b1[4], b3[4];
#pragma unroll
    for (int i = 0; i < 4; ++i)
      a[i] = *(const bf16x8*)(cur + rA + i * 1024);
#pragma unroll
    for (int j = 0; j < 4; ++j) {
      b1[j] = *(const bf16x8*)(cur + 8192  + rB + j * 1024);
      b3[j] = *(const bf16x8*)(cur + 16384 + rB + j * 1024);
    }
#pragma unroll
    for (int i = 0; i < 4; ++i)
#pragma unroll
      for (int j = 0; j < 4; ++j) {
        acc1[i][j] = __builtin_amdgcn_mfma_f32_16x16x32_bf16(a[i], b1[j], acc1[i][j], 0, 0, 0);
        acc3[i][j] = __builtin_amdgcn_mfma_f32_16x16x32_bf16(a[i], b3[j], acc3[i][j], 0, 0, 0);
      }
    __syncthreads();                            // drains next-tile loads + read fence
  }
#undef STAGE1

#pragma unroll
  for (int i = 0; i < 4; ++i) {
#pragma unroll
    for (int rr = 0; rr < 4; ++rr) {
      int slot = t0 + wm * 64 + i * 16 + lq * 4 + rr;
      if (slot < n_e) {
        unsigned short* orow = hbuf + (size_t)(nbase + slot) * I_DIM + i0 + wn * 64 + lm;
#pragma unroll
        for (int j = 0; j < 4; ++j) {
          float g = acc1[i][j][rr], u = acc3[i][j][rr];
          float hv = (g / (1.f + __expf(-g))) * u;
          orow[j * 16] = f2bf(hv);
        }
      }
    }
  }
}

// ---------------- GEMM2: 64 slots x 128 H, BK=32, split-K=2, 2-phase dbuf, swizzle ----------------
__global__ __launch_bounds__(256, 4) void gemm2(
    const unsigned short* __restrict__ hbuf,
    const unsigned short* __restrict__ w2t,
    const int* __restrict__ counts,
    const int* __restrict__ list_tok,
    const float* __restrict__ list_w,
    float* __restrict__ partial)
{
  __shared__ __align__(16) char smem[24576];   // 2 x 12KB
  int e = blockIdx.z;
  int nbase = 0;
#pragma unroll
  for (int i = 0; i < 8; ++i) if (i < e) nbase += counts[i];
  int n_e = counts[e];
  int ts = blockIdx.y >> 1, kh = blockIdx.y & 1;
  int t0 = ts * 64;
  if (t0 >= n_e) return;
  int h0 = blockIdx.x * 128;
  int k0 = kh * (I_DIM / 2);

  int tid = threadIdx.x;
  int r2 = tid >> 2;
  int sseg = (((tid & 3) ^ (r2 & 3)) * 8);

  int sr = t0 + r2; if (sr >= n_e) sr = n_e - 1;
  const char* gA  = (const char*)(hbuf + (size_t)(nbase + sr) * I_DIM + k0 + sseg);
  const char* gB0 = (const char*)(w2t + ((size_t)e * H_DIM + h0 + r2) * I_DIM + k0 + sseg);
  const char* gB1 = (const char*)(w2t + ((size_t)e * H_DIM + h0 + 64 + r2) * I_DIM + k0 + sseg);

  // per-buffer 12KB: A [0,4K) 64 slot-rows, B [4K,12K) 128 h-rows; buf1 at +12K
#define STAGE2(buf, kb) do {                              \
    gld16(gA  + (kb) * 2, (buf) + tid * 16);              \
    gld16(gB0 + (kb) * 2, (buf) + 4096 + tid * 16);       \
    gld16(gB1 + (kb) * 2, (buf) + 8192 + tid * 16);       \
  } while (0)

  int w = tid >> 6, lane = tid & 63, lm = lane & 15, lq = lane >> 4;
  int wm = w & 1, wn = w >> 1;
  int colx = (lq ^ (lm & 3)) * 16;
  int rA = (wm * 32 + lm) * 64 + colx;
  int rB = (wn * 64 + lm) * 64 + colx;

  f32x4 acc[2][4];
#pragma unroll
  for (int i = 0; i < 2; ++i)
#pragma unroll
    for (int j = 0; j < 4; ++j) acc[i][j] = (f32x4){0,0,0,0};

  STAGE2(smem, 0);
  __syncthreads();
  for (int kb = 0; kb < I_DIM / 2; kb += 32) {
    char* cur = smem + (((kb >> 5) & 1) ? 12288 : 0);
    char* nxt = smem + (((kb >> 5) & 1) ? 0 : 12288);
    if (kb + 32 < I_DIM / 2) STAGE2(nxt, kb + 32);
    bf16x8 a[2], b[4];
#pragma unroll
    for (int i = 0; i < 2; ++i)
      a[i] = *(const bf16x8*)(cur + rA + i * 1024);
#pragma unroll
    for (int j = 0; j < 4; ++j)
      b[j] = *(const bf16x8*)(cur + 4096 + rB + j * 1024);
#pragma unroll
    for (int i = 0; i < 2; ++i)
#pragma unroll
      for (int j = 0; j < 4; ++j)
        acc[i][j] = __builtin_amdgcn_mfma_f32_16x16x32_bf16(a[i], b[j], acc[i][j], 0, 0, 0);
    __syncthreads();
  }
#undef STAGE2

  int entv[2][4]; float wtv[2][4];
#pragma unroll
  for (int i = 0; i < 2; ++i)
#pragma unroll
    for (int rr = 0; rr < 4; ++rr) {
      int slot = t0 + wm * 32 + i * 16 + lq * 4 + rr;
      if (slot < n_e) { entv[i][rr] = list_tok[nbase + slot]; wtv[i][rr] = list_w[nbase + slot]; }
      else entv[i][rr] = -1;
    }
#pragma unroll
  for (int i = 0; i < 2; ++i)
#pragma unroll
    for (int j = 0; j < 4; ++j)
#pragma unroll
      for (int rr = 0; rr < 4; ++rr) {
        if (entv[i][rr] >= 0) {
          int t = entv[i][rr] >> 1, kk = entv[i][rr] & 1;
          int plane = kh * 2 + kk;
          partial[((size_t)plane * T_TOK + t) * H_DIM + h0 + wn * 64 + j * 16 + lm] =
              acc[i][j][rr] * wtv[i][rr];
        }
      }
}

// ---------------- out = sum of 4 partial planes ----------------
__global__ __launch_bounds__(256) void combine4(const float* __restrict__ partial,
                                                float* __restrict__ out)
{
  const size_t P = (size_t)T_TOK * H_DIM;
  size_t i = (size_t)(blockIdx.x * 256 + threadIdx.x) * 4;
  float4 a = *(const float4*)(partial + i);
  float4 b = *(const float4*)(partial + P + i);
  float4 c = *(const float4*)(partial + 2 * P + i);
  float4 d = *(const float4*)(partial + 3 * P + i);
  float4 o;
  o.x = a.x + b.x + c.x + d.x;
  o.y = a.y + b.y + c.y + d.y;
  o.z = a.z + b.z + c.z + d.z;
  o.w = a.w + b.w + c.w + d.w;
  *(float4*)(out + i) = o;
}

extern "C" void kernel_launch(void* const* d_in, const int* in_sizes, int n_in,
                              void* d_out, int out_size, void* d_ws, size_t ws_size,
                              hipStream_t stream) {
  const float* x  = (const float*)d_in[0];
  const float* gw = (const float*)d_in[1];
  const float* gb = (const float*)d_in[2];
  const float* w1 = (const float*)d_in[3];
  const float* w3 = (const float*)d_in[4];
  const float* w2 = (const float*)d_in[5];
  float* out = (float*)d_out;

  char* ws = (char*)d_ws;
  int*   counts   = (int*)(ws);            // 8 ints
  int*   rec_e    = (int*)(ws + 128);      // 4096 ints
  float* rec_w    = (float*)(ws + 16512);  // 4096 floats
  int*   list_tok = (int*)(ws + 32896);    // 4096 ints
  float* list_w   = (float*)(ws + 49280);  // 4096 floats
  const size_t MB = 1024ull * 1024ull;
  unsigned short* xb   = (unsigned short*)(ws + 1 * MB);    // 4 MB
  unsigned short* w1t  = (unsigned short*)(ws + 5 * MB);    // 32 MB  [E][I][H]
  float* partial       = (float*)(ws + 5 * MB);             // 32 MB  [4][T][H] (aliases w1t; dead after gemm1)
  unsigned short* w3t  = (unsigned short*)(ws + 37 * MB);   // 32 MB  [E][I][H]
  unsigned short* w2t  = (unsigned short*)(ws + 69 * MB);   // 32 MB  [E][H][I]
  unsigned short* hbuf = (unsigned short*)(ws + 101 * MB);  // 16 MB  [4096][I]

  gate_t13<<<2048, 256, 0, stream>>>(x, gw, gb, rec_e, rec_w, xb,
                                     w1, w3, w1t, w3t, w2, w2t);
  route8<<<8, 256, 0, stream>>>(rec_e, rec_w, counts, list_tok, list_w);
  gemm1<<<4096, 256, 0, stream>>>(xb, w1t, w3t, counts, list_tok, hbuf);
  gemm2<<<dim3(H_DIM / 128, 128, E_NUM), 256, 0, stream>>>(hbuf, w2t, counts, list_tok, list_w, partial);
  combine4<<<(T_TOK * H_DIM) / (256 * 4), 256, 0, stream>>>(partial, out);
}

// Round 9
// 347.074 us; speedup vs baseline: 1.3472x; 1.0363x over previous
//
#include <hip/hip_runtime.h>
#include <hip/hip_bf16.h>
#include <math.h>

typedef __attribute__((ext_vector_type(4))) float f32x4;
typedef __attribute__((ext_vector_type(8))) short bf16x8;

#define T_TOK 2048
#define H_DIM 1024
#define I_DIM 2048
#define E_NUM 8

// RNE float -> bf16
__device__ inline unsigned short f2bf(float f) {
  union { float f; unsigned int u; } v; v.f = f;
  unsigned int r = v.u + 0x7fffu + ((v.u >> 16) & 1u);
  return (unsigned short)(r >> 16);
}

// packed RNE: low u16 = bf16(a), high u16 = bf16(b) — single HW instruction
__device__ inline unsigned int cvtpk(float a, float b) {
  unsigned int r;
  asm("v_cvt_pk_bf16_f32 %0, %1, %2" : "=v"(r) : "v"(a), "v"(b));
  return r;
}

// async global->LDS, 16 bytes per lane
__device__ inline void gld16(const void* g, void* l) {
  __builtin_amdgcn_global_load_lds((const __attribute__((address_space(1))) void*)g,
                                   (__attribute__((address_space(3))) void*)l, 16, 0, 0);
}

// ---------------- kernel 1: gate (+x cast), 512 blocks ----------------
__global__ __launch_bounds__(256) void gate_k(
    const float* __restrict__ x, const float* __restrict__ gw, const float* __restrict__ gb,
    int* __restrict__ rec_e, float* __restrict__ rec_w, unsigned short* __restrict__ xb)
{
  int wv = threadIdx.x >> 6, lane = threadIdx.x & 63;
  int t = blockIdx.x * 4 + wv;
  const float* xr = x + (size_t)t * H_DIM;
  unsigned short* xo = xb + (size_t)t * H_DIM;
  float acc[8];
#pragma unroll
  for (int e = 0; e < 8; ++e) acc[e] = 0.f;
  for (int i = 0; i < H_DIM / 64; ++i) {
    int h = i * 64 + lane;
    float xv = xr[h];
    xo[h] = f2bf(xv);
    const float4* g = (const float4*)(gw + (size_t)h * 8);
    float4 g0 = g[0], g1 = g[1];
    acc[0] += xv * g0.x; acc[1] += xv * g0.y; acc[2] += xv * g0.z; acc[3] += xv * g0.w;
    acc[4] += xv * g1.x; acc[5] += xv * g1.y; acc[6] += xv * g1.z; acc[7] += xv * g1.w;
  }
#pragma unroll
  for (int s = 1; s < 64; s <<= 1) {
#pragma unroll
    for (int e = 0; e < 8; ++e) acc[e] += __shfl_xor(acc[e], s);
  }
  if (lane == 0) {
    float l[8];
#pragma unroll
    for (int e = 0; e < 8; ++e) l[e] = acc[e] + gb[e];
    int e0 = 0;
    for (int e = 1; e < 8; ++e) if (l[e] > l[e0]) e0 = e;
    int e1 = (e0 == 0) ? 1 : 0;
    for (int e = 0; e < 8; ++e) if (e != e0 && l[e] > l[e1]) e1 = e;
    float w0 = 1.f / (1.f + expf(l[e1] - l[e0]));
    rec_e[t * 2]     = e0; rec_e[t * 2 + 1] = e1;
    rec_w[t * 2]     = w0; rec_w[t * 2 + 1] = 1.f - w0;
  }
}

// ---------------- routing: 8 blocks, one per expert ----------------
__global__ __launch_bounds__(256) void route8(
    const int* __restrict__ rec_e, const float* __restrict__ rec_w,
    int* __restrict__ counts_g, int* __restrict__ list_tok, float* __restrict__ list_w)
{
  __shared__ int cnt[8];
  __shared__ int fill;
  int e = blockIdx.x;
  int tid = threadIdx.x;
  if (tid < 8) cnt[tid] = 0;
  if (tid == 0) fill = 0;
  __syncthreads();
  int e_loc[16];
  int c_loc[8];
#pragma unroll
  for (int k = 0; k < 8; ++k) c_loc[k] = 0;
#pragma unroll
  for (int it = 0; it < 16; ++it) {
    e_loc[it] = rec_e[it * 256 + tid] & 7;
    c_loc[e_loc[it]]++;
  }
#pragma unroll
  for (int k = 0; k < 8; ++k) if (c_loc[k]) atomicAdd(&cnt[k], c_loc[k]);
  __syncthreads();
  if (e == 0 && tid < 8) counts_g[tid] = cnt[tid];
  int base = 0;
#pragma unroll
  for (int k = 0; k < 8; ++k) if (k < e) base += cnt[k];
#pragma unroll
  for (int it = 0; it < 16; ++it) {
    if (e_loc[it] == e) {
      int i = it * 256 + tid;
      int pos = atomicAdd(&fill, 1);
      list_tok[base + pos] = i;            // i = (t<<1)|k
      list_w[base + pos]   = rec_w[i];
    }
  }
}

// ---------------- gemm1: 128x128 dual (B1,B3), BK=32, 2-phase dbuf ----------------
// B read DIRECTLY from fp32 w1/w3 (coalesced 512B rows) with in-register cvt_pk
// transpose into LDS. B-panel swizzle: logical chunk lc of row r at physical
// lc ^ ((r>>3)&3). A path (xb via global_load_lds, chunk = lc ^ (r&3)) unchanged.
__global__ __launch_bounds__(256, 2) void gemm1(
    const unsigned short* __restrict__ xb,
    const float* __restrict__ w1,
    const float* __restrict__ w3,
    const int* __restrict__ counts,
    const int* __restrict__ list_tok,
    unsigned short* __restrict__ hbuf)
{
  __shared__ __align__(16) char smem[49152];   // 2 x 24KB: A 8K | B1 8K | B3 8K
  int bx = blockIdx.x;
  int e = bx >> 9;
  int y = (bx >> 4) & 31;
  int ix = bx & 15;
  int nbase = 0;
#pragma unroll
  for (int i = 0; i < 8; ++i) if (i < e) nbase += counts[i];
  int n_e = counts[e];
  int t0 = y * 128;
  if (t0 >= n_e) return;
  int i0 = ix * 128;

  int tid = threadIdx.x;
  int r2 = tid >> 2;
  int sseg = (((tid & 3) ^ (r2 & 3)) * 8);     // A pre-swizzle (elements)

  int sr0 = t0 + r2;       if (sr0 >= n_e) sr0 = n_e - 1;
  int sr1 = t0 + 64 + r2;  if (sr1 >= n_e) sr1 = n_e - 1;
  int tok0 = list_tok[nbase + sr0] >> 1;
  int tok1 = list_tok[nbase + sr1] >> 1;
  const char* gA0 = (const char*)(xb + (size_t)tok0 * H_DIM + sseg);
  const char* gA1 = (const char*)(xb + (size_t)tok1 * H_DIM + sseg);

#define STAGEA1(buf, kb) do {                             \
    gld16(gA0 + (kb) * 2, (buf) + tid * 16);              \
    gld16(gA1 + (kb) * 2, (buf) + 4096 + tid * 16);       \
  } while (0)

  // B fill: thread gq=tid>>5 handles H rows gq*4..+3; lif=tid&31 handles I cols lif*4..+3
  int gq = tid >> 5, lif = tid & 31;
  const float* pB1 = w1 + (size_t)e * ((size_t)H_DIM * I_DIM) + (size_t)(gq * 4) * I_DIM + i0 + lif * 4;
  const float* pB3 = w3 + (size_t)e * ((size_t)H_DIM * I_DIM) + (size_t)(gq * 4) * I_DIM + i0 + lif * 4;
  // write base: r = lif*4 (+k), lc = gq>>1, f(r) = (lif>>1)&3, intra-chunk byte (gq&1)*8
  int wb = (lif * 4) * 64 + (((gq >> 1) ^ ((lif >> 1) & 3)) * 16) + (gq & 1) * 8;

  float4 v0, v1, v2, v3, q0, q1, q2, q3;
#define LOADB1(kb) do {                                                        \
    const float* p1 = pB1 + (size_t)(kb) * I_DIM;                              \
    const float* p3 = pB3 + (size_t)(kb) * I_DIM;                              \
    v0 = *(const float4*)(p1);             v1 = *(const float4*)(p1 + I_DIM);  \
    v2 = *(const float4*)(p1 + 2 * I_DIM); v3 = *(const float4*)(p1 + 3 * I_DIM); \
    q0 = *(const float4*)(p3);             q1 = *(const float4*)(p3 + I_DIM);  \
    q2 = *(const float4*)(p3 + 2 * I_DIM); q3 = *(const float4*)(p3 + 3 * I_DIM); \
  } while (0)
#define WRITEB1(buf) do {                                                      \
    char* c1 = (buf) + 8192 + wb; char* c3 = (buf) + 16384 + wb;               \
    _Pragma("unroll") for (int k = 0; k < 4; ++k) {                            \
      uint2 d1; d1.x = cvtpk(v0[k], v1[k]); d1.y = cvtpk(v2[k], v3[k]);        \
      uint2 d3; d3.x = cvtpk(q0[k], q1[k]); d3.y = cvtpk(q2[k], q3[k]);        \
      *(uint2*)(c1 + k * 64) = d1;                                             \
      *(uint2*)(c3 + k * 64) = d3;                                             \
    }                                                                          \
  } while (0)

  int w = tid >> 6, lane = tid & 63, lm = lane & 15, lq = lane >> 4;
  int wm = w & 1, wn = w >> 1;
  int lmh = lm >> 3;
  int colA = (lq ^ (lm & 3)) * 16;
  int rA = (wm * 64 + lm) * 64 + colA;         // + i*1024 per row block
  int rBb = (wn * 64 + lm) * 64;               // + j*1024 + cb[j]
  int cb[4];
#pragma unroll
  for (int j = 0; j < 4; ++j) cb[j] = (lq ^ ((j * 2 + lmh) & 3)) * 16;

  f32x4 acc1[4][4], acc3[4][4];
#pragma unroll
  for (int i = 0; i < 4; ++i)
#pragma unroll
    for (int j = 0; j < 4; ++j) { acc1[i][j] = (f32x4){0,0,0,0}; acc3[i][j] = (f32x4){0,0,0,0}; }

  LOADB1(0);
  STAGEA1(smem, 0);
  WRITEB1(smem);
  LOADB1(32);
  __syncthreads();                              // buf0 ready
  for (int t = 0; t < 32; ++t) {
    char* cur = smem + (t & 1) * 24576;
    char* nxt = smem + ((t + 1) & 1) * 24576;
    if (t < 31) STAGEA1(nxt, (t + 1) * 32);
    bf16x8 a[4], b1[4], b3[4];
#pragma unroll
    for (int i = 0; i < 4; ++i)
      a[i] = *(const bf16x8*)(cur + rA + i * 1024);
#pragma unroll
    for (int j = 0; j < 4; ++j) {
      b1[j] = *(const bf16x8*)(cur + 8192  + rBb + j * 1024 + cb[j]);
      b3[j] = *(const bf16x8*)(cur + 16384 + rBb + j * 1024 + cb[j]);
    }
    if (t < 31) WRITEB1(nxt);                   // consumes LOADB1(t+1) regs
    if (t < 30) LOADB1((t + 2) * 32);           // regs free after WRITEB1
#pragma unroll
    for (int i = 0; i < 4; ++i)
#pragma unroll
      for (int j = 0; j < 4; ++j) {
        acc1[i][j] = __builtin_amdgcn_mfma_f32_16x16x32_bf16(a[i], b1[j], acc1[i][j], 0, 0, 0);
        acc3[i][j] = __builtin_amdgcn_mfma_f32_16x16x32_bf16(a[i], b3[j], acc3[i][j], 0, 0, 0);
      }
    __syncthreads();                            // drains A gld16 + B ds_writes: nxt ready
  }
#undef STAGEA1
#undef LOADB1
#undef WRITEB1

#pragma unroll
  for (int i = 0; i < 4; ++i) {
#pragma unroll
    for (int rr = 0; rr < 4; ++rr) {
      int slot = t0 + wm * 64 + i * 16 + lq * 4 + rr;
      if (slot < n_e) {
        unsigned short* orow = hbuf + (size_t)(nbase + slot) * I_DIM + i0 + wn * 64 + lm;
#pragma unroll
        for (int j = 0; j < 4; ++j) {
          float g = acc1[i][j][rr], u = acc3[i][j][rr];
          float hv = (g / (1.f + __expf(-g))) * u;
          orow[j * 16] = f2bf(hv);
        }
      }
    }
  }
}

// ---------------- GEMM2: 64 slots x 128 H, BK=32, split-K=2, direct-fp32 B ----------------
__global__ __launch_bounds__(256, 4) void gemm2(
    const unsigned short* __restrict__ hbuf,
    const float* __restrict__ w2,
    const int* __restrict__ counts,
    const int* __restrict__ list_tok,
    const float* __restrict__ list_w,
    float* __restrict__ partial)
{
  __shared__ __align__(16) char smem[24576];   // 2 x 12KB: A 4K | B 8K
  int e = blockIdx.z;
  int nbase = 0;
#pragma unroll
  for (int i = 0; i < 8; ++i) if (i < e) nbase += counts[i];
  int n_e = counts[e];
  int ts = blockIdx.y >> 1, kh = blockIdx.y & 1;
  int t0 = ts * 64;
  if (t0 >= n_e) return;
  int h0 = blockIdx.x * 128;
  int k0 = kh * (I_DIM / 2);

  int tid = threadIdx.x;
  int r2 = tid >> 2;
  int sseg = (((tid & 3) ^ (r2 & 3)) * 8);

  int sr = t0 + r2; if (sr >= n_e) sr = n_e - 1;
  const char* gA = (const char*)(hbuf + (size_t)(nbase + sr) * I_DIM + k0 + sseg);

#define STAGEA2(buf, kb) do { gld16(gA + (kb) * 2, (buf) + tid * 16); } while (0)

  // B fill: rows = i (K), cols = h. gq=tid>>5 -> i rows gq*4..+3; lif=tid&31 -> h cols lif*4..+3
  int gq = tid >> 5, lif = tid & 31;
  const float* pB = w2 + (size_t)e * ((size_t)H_DIM * I_DIM) + (size_t)(k0 + gq * 4) * H_DIM + h0 + lif * 4;
  int wb = (lif * 4) * 64 + (((gq >> 1) ^ ((lif >> 1) & 3)) * 16) + (gq & 1) * 8;

  float4 v0, v1, v2, v3;
#define LOADB2(kb) do {                                                        \
    const float* p = pB + (size_t)(kb) * H_DIM;                                \
    v0 = *(const float4*)(p);             v1 = *(const float4*)(p + H_DIM);    \
    v2 = *(const float4*)(p + 2 * H_DIM); v3 = *(const float4*)(p + 3 * H_DIM); \
  } while (0)
#define WRITEB2(buf) do {                                                      \
    char* c = (buf) + 4096 + wb;                                               \
    _Pragma("unroll") for (int k = 0; k < 4; ++k) {                            \
      uint2 d; d.x = cvtpk(v0[k], v1[k]); d.y = cvtpk(v2[k], v3[k]);           \
      *(uint2*)(c + k * 64) = d;                                               \
    }                                                                          \
  } while (0)

  int w = tid >> 6, lane = tid & 63, lm = lane & 15, lq = lane >> 4;
  int wm = w & 1, wn = w >> 1;
  int lmh = lm >> 3;
  int colA = (lq ^ (lm & 3)) * 16;
  int rA = (wm * 32 + lm) * 64 + colA;
  int rBb = (wn * 64 + lm) * 64;
  int cb[4];
#pragma unroll
  for (int j = 0; j < 4; ++j) cb[j] = (lq ^ ((j * 2 + lmh) & 3)) * 16;

  f32x4 acc[2][4];
#pragma unroll
  for (int i = 0; i < 2; ++i)
#pragma unroll
    for (int j = 0; j < 4; ++j) acc[i][j] = (f32x4){0,0,0,0};

  LOADB2(0);
  STAGEA2(smem, 0);
  WRITEB2(smem);
  LOADB2(32);
  __syncthreads();
  for (int t = 0; t < 32; ++t) {
    char* cur = smem + (t & 1) * 12288;
    char* nxt = smem + ((t + 1) & 1) * 12288;
    if (t < 31) STAGEA2(nxt, (t + 1) * 32);
    bf16x8 a[2], b[4];
#pragma unroll
    for (int i = 0; i < 2; ++i)
      a[i] = *(const bf16x8*)(cur + rA + i * 1024);
#pragma unroll
    for (int j = 0; j < 4; ++j)
      b[j] = *(const bf16x8*)(cur + 4096 + rBb + j * 1024 + cb[j]);
    if (t < 31) WRITEB2(nxt);
    if (t < 30) LOADB2((t + 2) * 32);
#pragma unroll
    for (int i = 0; i < 2; ++i)
#pragma unroll
      for (int j = 0; j < 4; ++j)
        acc[i][j] = __builtin_amdgcn_mfma_f32_16x16x32_bf16(a[i], b[j], acc[i][j], 0, 0, 0);
    __syncthreads();
  }
#undef STAGEA2
#undef LOADB2
#undef WRITEB2

  int entv[2][4]; float wtv[2][4];
#pragma unroll
  for (int i = 0; i < 2; ++i)
#pragma unroll
    for (int rr = 0; rr < 4; ++rr) {
      int slot = t0 + wm * 32 + i * 16 + lq * 4 + rr;
      if (slot < n_e) { entv[i][rr] = list_tok[nbase + slot]; wtv[i][rr] = list_w[nbase + slot]; }
      else entv[i][rr] = -1;
    }
#pragma unroll
  for (int i = 0; i < 2; ++i)
#pragma unroll
    for (int j = 0; j < 4; ++j)
#pragma unroll
      for (int rr = 0; rr < 4; ++rr) {
        if (entv[i][rr] >= 0) {
          int t = entv[i][rr] >> 1, kk = entv[i][rr] & 1;
          int plane = kh * 2 + kk;
          partial[((size_t)plane * T_TOK + t) * H_DIM + h0 + wn * 64 + j * 16 + lm] =
              acc[i][j][rr] * wtv[i][rr];
        }
      }
}

// ---------------- out = sum of 4 partial planes ----------------
__global__ __launch_bounds__(256) void combine4(const float* __restrict__ partial,
                                                float* __restrict__ out)
{
  const size_t P = (size_t)T_TOK * H_DIM;
  size_t i = (size_t)(blockIdx.x * 256 + threadIdx.x) * 4;
  float4 a = *(const float4*)(partial + i);
  float4 b = *(const float4*)(partial + P + i);
  float4 c = *(const float4*)(partial + 2 * P + i);
  float4 d = *(const float4*)(partial + 3 * P + i);
  float4 o;
  o.x = a.x + b.x + c.x + d.x;
  o.y = a.y + b.y + c.y + d.y;
  o.z = a.z + b.z + c.z + d.z;
  o.w = a.w + b.w + c.w + d.w;
  *(float4*)(out + i) = o;
}

extern "C" void kernel_launch(void* const* d_in, const int* in_sizes, int n_in,
                              void* d_out, int out_size, void* d_ws, size_t ws_size,
                              hipStream_t stream) {
  const float* x  = (const float*)d_in[0];
  const float* gw = (const float*)d_in[1];
  const float* gb = (const float*)d_in[2];
  const float* w1 = (const float*)d_in[3];
  const float* w3 = (const float*)d_in[4];
  const float* w2 = (const float*)d_in[5];
  float* out = (float*)d_out;

  char* ws = (char*)d_ws;
  int*   counts   = (int*)(ws);            // 8 ints
  int*   rec_e    = (int*)(ws + 128);      // 4096 ints
  float* rec_w    = (float*)(ws + 16512);  // 4096 floats
  int*   list_tok = (int*)(ws + 32896);    // 4096 ints
  float* list_w   = (float*)(ws + 49280);  // 4096 floats
  const size_t MB = 1024ull * 1024ull;
  unsigned short* xb = (unsigned short*)(ws + 1 * MB);   // 4 MB
  float* partial     = (float*)(ws + 5 * MB);            // 32 MB [4][T][H]
  unsigned short* hbuf = (unsigned short*)(ws + 101 * MB); // 16 MB [4096][I]

  gate_k<<<512, 256, 0, stream>>>(x, gw, gb, rec_e, rec_w, xb);
  route8<<<8, 256, 0, stream>>>(rec_e, rec_w, counts, list_tok, list_w);
  gemm1<<<4096, 256, 0, stream>>>(xb, w1, w3, counts, list_tok, hbuf);
  gemm2<<<dim3(H_DIM / 128, 128, E_NUM), 256, 0, stream>>>(hbuf, w2, counts, list_tok, list_w, partial);
  combine4<<<(T_TOK * H_DIM) / (256 * 4), 256, 0, stream>>>(partial, out);
}